// Round 19
// baseline (77.427 us; speedup 1.0000x reference)
//
#include <hip/hip_runtime.h>
#include <hip/hip_bf16.h>

// B=8, T=4096, C=1024, HS=64. Single attention head, causal, scale = C^-0.5.
// Pipeline: wprep ; proj (counted-vmcnt) ; flash (32x32 MFMA, 32 q-rows/wave,
//           128-row q-tiles, 4-way KV split, LDS dbuf staging, in-register P
//           via cvt_pk + v_permlane32_swap, bf16 partials) ; combine.
// Q is pre-scaled by log2(e)/32 in proj, so QK^T is directly log2-domain.
// qt = (g + 4b) & 31: load-balanced under BOTH consecutive-id and stride-256
// block->CU dispatch (any 4-8 consecutive ids span qt values 4 apart).

typedef __attribute__((ext_vector_type(8))) short short8;
typedef __attribute__((ext_vector_type(8))) unsigned short ushort8;
typedef __attribute__((ext_vector_type(4))) float f32x4;
typedef __attribute__((ext_vector_type(16))) float f32x16;
typedef __attribute__((ext_vector_type(4))) unsigned int u32x4;

#define NB 8
#define NT 4096
#define NC 1024
#define NH 64

__device__ __forceinline__ unsigned short f2bf(float f) {
    unsigned int u = __builtin_bit_cast(unsigned int, f);
    u += 0x7fffu + ((u >> 16) & 1u);   // RNE
    return (unsigned short)(u >> 16);
}

__device__ __forceinline__ float bf2f(unsigned short u) {
    return __builtin_bit_cast(float, (unsigned int)u << 16);
}

__device__ __forceinline__ unsigned cvt_pk_bf16(float lo, float hi) {
    unsigned r;
    asm("v_cvt_pk_bf16_f32 %0, %1, %2" : "=v"(r) : "v"(lo), "v"(hi));
    return r;
}

// async global->LDS, 16B per lane; LDS dest = wave-uniform base + lane*16
#define GLOAD16(gp, lp)                                                        \
    __builtin_amdgcn_global_load_lds(                                          \
        (const __attribute__((address_space(1))) void*)(gp),                   \
        (__attribute__((address_space(3))) void*)(lp), 16, 0, 0)

// ---------------- W prep: Wt[n][c] = W_{n/64}[c][n%64] as bf16 -----------------
__global__ __launch_bounds__(256) void wprep_kernel(
    const float* __restrict__ Wk, const float* __restrict__ Wq,
    const float* __restrict__ Wv, unsigned short* __restrict__ Wt)
{
    int n = blockIdx.x;            // 0..191
    int which = n >> 6, h = n & 63;
    const float* W = (which == 0) ? Wk : (which == 1) ? Wq : Wv;
    for (int c = threadIdx.x; c < NC; c += 256)
        Wt[(size_t)n * NC + c] = f2bf(W[(size_t)c * NH + h]);
}

// ---------------- Projection GEMM: [32768 x 1024] @ [1024 x 192] ---------------
// Counted-vmcnt pipeline: BK=32, 4 LDS buffers (20 KB each), depth-2 prefetch.
__global__ __launch_bounds__(256, 2) void proj_kernel(
    const float* __restrict__ x, const unsigned short* __restrict__ Wt,
    unsigned short* __restrict__ qws, unsigned short* __restrict__ kws,
    unsigned short* __restrict__ vtws)
{
    __shared__ char lds[4][20480];   // [buf]: A at 0 (8 KB), B at 8192 (12 KB)

    const int lane = threadIdx.x & 63;
    const int wave = threadIdx.x >> 6;
    const int l15 = lane & 15;
    const int kg = lane >> 4;                  // 0..3
    const int m0 = blockIdx.x * 64;

    const int agS = (lane & 7) ^ (lane >> 3);
    const float* aSrc[2];
#pragma unroll
    for (int j = 0; j < 2; ++j) {
        int i = wave * 2 + j;
        int r = 8 * i + (lane >> 3);
        aSrc[j] = x + (size_t)(m0 + r) * NC + agS * 4;
    }
    const int bgS = (lane & 3) ^ ((lane >> 2) & 3);
    const unsigned short* bSrc[3];
#pragma unroll
    for (int j = 0; j < 3; ++j) {
        int u = wave * 3 + j;
        int r = 16 * u + (lane >> 2);
        bSrc[j] = Wt + (size_t)r * NC + bgS * 8;
    }

    f32x4 acc[12];
#pragma unroll
    for (int i = 0; i < 12; ++i) acc[i] = f32x4{0.f, 0.f, 0.f, 0.f};

#define STAGE_CHUNK(c)                                                         \
    do {                                                                       \
        char* base_ = lds[(c) & 3];                                            \
        _Pragma("unroll")                                                      \
        for (int j = 0; j < 2; ++j)                                            \
            GLOAD16(aSrc[j] + (c) * 32, base_ + (wave * 2 + j) * 1024);        \
        _Pragma("unroll")                                                      \
        for (int j = 0; j < 3; ++j)                                            \
            GLOAD16(bSrc[j] + (c) * 32, base_ + 8192 + (wave * 3 + j) * 1024); \
    } while (0)

    STAGE_CHUNK(0);
    STAGE_CHUNK(1);

    for (int kc = 0; kc < 32; ++kc) {
        if (kc < 30) {
            STAGE_CHUNK(kc + 2);
            asm volatile("s_waitcnt vmcnt(10)" ::: "memory");
        } else if (kc == 30) {
            asm volatile("s_waitcnt vmcnt(5)" ::: "memory");
        } else {
            asm volatile("s_waitcnt vmcnt(0)" ::: "memory");
        }
        __builtin_amdgcn_sched_barrier(0);
        __builtin_amdgcn_s_barrier();

        const char* Ab = lds[kc & 3];
        const char* Bb = lds[kc & 3] + 8192;
        {
            const int r = wave * 16 + l15;
            const int g0 = kg * 2;
            f32x4 a0 = *(const f32x4*)(Ab + r * 128 + ((g0 ^ (r & 7)) * 16));
            f32x4 a1 = *(const f32x4*)(Ab + r * 128 + (((g0 + 1) ^ (r & 7)) * 16));
            short8 a;
            a[0] = (short)f2bf(a0[0]); a[1] = (short)f2bf(a0[1]);
            a[2] = (short)f2bf(a0[2]); a[3] = (short)f2bf(a0[3]);
            a[4] = (short)f2bf(a1[0]); a[5] = (short)f2bf(a1[1]);
            a[6] = (short)f2bf(a1[2]); a[7] = (short)f2bf(a1[3]);
#pragma unroll
            for (int nt = 0; nt < 12; ++nt) {
                int rb = nt * 16 + l15;
                short8 bfrag = *(const short8*)(
                    Bb + rb * 64 + ((kg ^ (rb & 3)) * 16));
                acc[nt] = __builtin_amdgcn_mfma_f32_16x16x32_bf16(a, bfrag, acc[nt], 0, 0, 0);
            }
        }
    }
#undef STAGE_CHUNK

    const float cs = 0.04508422f;   // log2(e) / 32  (folded into q)
    const int crow0 = m0 + wave * 16 + (kg << 2);
#pragma unroll
    for (int nt = 0; nt < 12; ++nt) {
        int n = nt * 16 + l15;
        int which = n >> 6;
        int h = n & 63;
#pragma unroll
        for (int r = 0; r < 4; ++r) {
            int gm = crow0 + r;
            float av = acc[nt][r];
            if (which == 1) av *= cs;
            unsigned short v = f2bf(av);
            if (which == 0) {
                kws[(size_t)gm * NH + h] = v;
            } else if (which == 1) {
                qws[(size_t)gm * NH + h] = v;
            } else {
                int bb = gm >> 12, tt = gm & 4095;
                vtws[((size_t)(bb * NH + h)) * NT + tt] = v;
            }
        }
    }
}

// ---------------- Flash attention (32x32 MFMA, 128-row q-tiles, 4-way split) ----
// 1024 blocks: id = g*32 + p*8 + b. qt = (g + 4b)&31 -> any group of 4-8
// consecutive ids spans qt values 4 apart (balanced under consecutive-id
// dispatch) AND stride-256 groups balance too. b = id&7 keeps XCD/L2 affinity.
__global__ __launch_bounds__(256, 4) void flash_kernel(
    const unsigned short* __restrict__ qws, const unsigned short* __restrict__ kws,
    const unsigned short* __restrict__ vtws,
    unsigned short* __restrict__ opart, float* __restrict__ mlpart)
{
    __shared__ unsigned short Kbuf[2][64 * 64];    // 64 keys x 64 d, 128 B rows
    __shared__ unsigned short Vbuf[2][64 * 64];    // 64 d x 64 keys (V^T)

    const int id = blockIdx.x;
    const int g = id >> 5;
    const int p = (id >> 3) & 3;
    const int b = id & 7;
    const int qt = (g + 4 * b) & 31;   // dispatch-robust balance mapping
    const int n = 2 * qt + 2;          // KV tiles for this 128-row q-tile
    const int len = (n + 3) >> 2;
    const int k0 = p * len;
    const int k1 = (k0 + len < n) ? (k0 + len) : n;

    float* mlp = mlpart + (size_t)id * 256;
    unsigned short* op = opart + (size_t)id * 8192;

    const int lane = threadIdx.x & 63;
    const int wave = threadIdx.x >> 6;
    const int l31 = lane & 31;
    const int hi = lane >> 5;
    const int rsw = lane & 7;          // row swizzle bits for frag reads

    // staging sources (pre-inverse-swizzled)
    const int sg = (lane & 7) ^ (lane >> 3);
    const unsigned short* kSrc[2];
    const unsigned short* vSrc[2];
#pragma unroll
    for (int j = 0; j < 2; ++j) {
        int r = 16 * wave + 8 * j + (lane >> 3);   // tile-local row 0..63
        kSrc[j] = kws + ((size_t)(b * NT) + r) * NH + sg * 8;
        vSrc[j] = vtws + ((size_t)(b * NH + r)) * NT + sg * 8;
    }

    // Q fragments (B-operand): lane holds Q[d = s*16 + 8*hi + j][q = l31]
    const int qmin = qt * 128 + wave * 32;
    short8 qf[4];
    {
        const char* qp = (const char*)(qws + ((size_t)(b * NT) + qmin + l31) * NH);
#pragma unroll
        for (int s = 0; s < 4; ++s)
            qf[s] = *(const short8*)(qp + s * 32 + hi * 16);
    }

    f32x16 o0, o1;                     // O^T: d-tiles 0..31 / 32..63, q = l31
#pragma unroll
    for (int i = 0; i < 16; ++i) { o0[i] = 0.f; o1[i] = 0.f; }
    float m_r = -INFINITY;
    float l_r = 0.f;                   // per-lane partial (own 32 keys per tile)

    const int kst = (k0 < n) ? k0 : (n - 1);
#pragma unroll
    for (int j = 0; j < 2; ++j) {
        int i = 2 * wave + j;
        GLOAD16(kSrc[j] + (size_t)kst * 64 * NH, (char*)Kbuf[0] + i * 1024);
        GLOAD16(vSrc[j] + (size_t)kst * 64,      (char*)Vbuf[0] + i * 1024);
    }
    __syncthreads();

    int cur = 0;
    for (int kv = k0; kv < k1; ++kv) {
        if (kv + 1 < k1) {
#pragma unroll
            for (int j = 0; j < 2; ++j) {
                int i = 2 * wave + j;
                GLOAD16(kSrc[j] + (size_t)(kv + 1) * 64 * NH,
                        (char*)Kbuf[cur ^ 1] + i * 1024);
                GLOAD16(vSrc[j] + (size_t)(kv + 1) * 64,
                        (char*)Vbuf[cur ^ 1] + i * 1024);
            }
        }

        const char* Kb = (const char*)Kbuf[cur];
        const char* Vb = (const char*)Vbuf[cur];

        // S^T = mfma32(K, Q): st0 = keys kv*64+0..31, st1 = +32..63; q = l31
        f32x16 st0, st1;
#pragma unroll
        for (int i = 0; i < 16; ++i) { st0[i] = 0.f; st1[i] = 0.f; }
        __builtin_amdgcn_s_setprio(1);
#pragma unroll
        for (int s = 0; s < 4; ++s) {
            int gl = s * 2 + hi;                    // 16B granule in 128B row
            short8 ka = *(const short8*)(Kb + l31 * 128 + ((gl ^ rsw) << 4));
            short8 kb = *(const short8*)(Kb + (32 + l31) * 128 + ((gl ^ rsw) << 4));
            st0 = __builtin_amdgcn_mfma_f32_32x32x16_bf16(ka, qf[s], st0, 0, 0, 0);
            st1 = __builtin_amdgcn_mfma_f32_32x32x16_bf16(kb, qf[s], st1, 0, 0, 0);
        }
        __builtin_amdgcn_s_setprio(0);

        // causal mask (elementwise only when tile can cross the diagonal)
        const int kb0 = kv * 64;
        if (kb0 + 63 > qmin) {
            const int qg = qmin + l31;
#pragma unroll
            for (int r = 0; r < 16; ++r) {
                int key = kb0 + (r & 3) + 8 * (r >> 2) + 4 * hi;
                if (key > qg) st0[r] = -1e30f;
                if (key + 32 > qg) st1[r] = -1e30f;
            }
        }

        // lane-local max over own 32 values (max3-friendly triples)
        float lmax;
        {
            float a0 = fmaxf(fmaxf(st0[0], st0[1]), st0[2]);
            float a1 = fmaxf(fmaxf(st0[3], st0[4]), st0[5]);
            float a2 = fmaxf(fmaxf(st0[6], st0[7]), st0[8]);
            float a3 = fmaxf(fmaxf(st0[9], st0[10]), st0[11]);
            float a4 = fmaxf(fmaxf(st0[12], st0[13]), st0[14]);
            float a5 = fmaxf(fmaxf(st0[15], st1[0]), st1[1]);
            float a6 = fmaxf(fmaxf(st1[2], st1[3]), st1[4]);
            float a7 = fmaxf(fmaxf(st1[5], st1[6]), st1[7]);
            float a8 = fmaxf(fmaxf(st1[8], st1[9]), st1[10]);
            float a9 = fmaxf(fmaxf(st1[11], st1[12]), st1[13]);
            float aa = fmaxf(st1[14], st1[15]);
            float b0 = fmaxf(fmaxf(a0, a1), a2);
            float b1 = fmaxf(fmaxf(a3, a4), a5);
            float b2 = fmaxf(fmaxf(a6, a7), a8);
            float b3 = fmaxf(a9, aa);
            lmax = fmaxf(fmaxf(b0, b1), fmaxf(b2, b3));
        }

        // defer-max: rescale only when some row grew past m+8 (rare)
        if (!__all(lmax <= m_r + 8.0f)) {
            float pmax = fmaxf(lmax, __shfl_xor(lmax, 32));
            float mn = fmaxf(m_r, pmax);
            float alpha = __builtin_amdgcn_exp2f(m_r - mn);
            m_r = mn;
            l_r *= alpha;
#pragma unroll
            for (int r = 0; r < 16; ++r) { o0[r] *= alpha; o1[r] *= alpha; }
        }

        // P = exp2(S - m); accumulate per-lane partial l (balanced tree)
#pragma unroll
        for (int r = 0; r < 16; ++r) {
            st0[r] = __builtin_amdgcn_exp2f(st0[r] - m_r);
            st1[r] = __builtin_amdgcn_exp2f(st1[r] - m_r);
        }
        {
            float q0 = (st0[0] + st0[1]) + (st0[2] + st0[3]);
            float q1 = (st0[4] + st0[5]) + (st0[6] + st0[7]);
            float q2 = (st0[8] + st0[9]) + (st0[10] + st0[11]);
            float q3 = (st0[12] + st0[13]) + (st0[14] + st0[15]);
            float q4 = (st1[0] + st1[1]) + (st1[2] + st1[3]);
            float q5 = (st1[4] + st1[5]) + (st1[6] + st1[7]);
            float q6 = (st1[8] + st1[9]) + (st1[10] + st1[11]);
            float q7 = (st1[12] + st1[13]) + (st1[14] + st1[15]);
            l_r += ((q0 + q1) + (q2 + q3)) + ((q4 + q5) + (q6 + q7));
        }

        // per key-tile: P^T B-frags via cvt_pk + permlane32_swap, then PV
        __builtin_amdgcn_s_setprio(1);
#pragma unroll
        for (int kt = 0; kt < 2; ++kt) {
            const f32x16& st = kt ? st1 : st0;
            unsigned w0 = cvt_pk_bf16(st[0], st[1]),   w1 = cvt_pk_bf16(st[2], st[3]);
            unsigned w2 = cvt_pk_bf16(st[4], st[5]),   w3 = cvt_pk_bf16(st[6], st[7]);
            unsigned w4 = cvt_pk_bf16(st[8], st[9]),   w5 = cvt_pk_bf16(st[10], st[11]);
            unsigned w6 = cvt_pk_bf16(st[12], st[13]), w7 = cvt_pk_bf16(st[14], st[15]);
            asm("v_permlane32_swap_b32 %0, %1" : "+v"(w0), "+v"(w2));
            asm("v_permlane32_swap_b32 %0, %1" : "+v"(w1), "+v"(w3));
            asm("v_permlane32_swap_b32 %0, %1" : "+v"(w4), "+v"(w6));
            asm("v_permlane32_swap_b32 %0, %1" : "+v"(w5), "+v"(w7));
            u32x4 wA, wB;
            wA[0] = w0; wA[1] = w1; wA[2] = w2; wA[3] = w3;
            wB[0] = w4; wB[1] = w5; wB[2] = w6; wB[3] = w7;
            short8 pfA = __builtin_bit_cast(short8, wA);
            short8 pfB = __builtin_bit_cast(short8, wB);
#pragma unroll
            for (int w = 0; w < 2; ++w) {           // key window within tile
                short8 pf = w ? pfB : pfA;
                int gv = (kt * 2 + w) * 2 + hi;     // granule over 64-key row
                short8 va = *(const short8*)(Vb + l31 * 128 + ((gv ^ rsw) << 4));
                short8 vb = *(const short8*)(Vb + (32 + l31) * 128 + ((gv ^ rsw) << 4));
                o0 = __builtin_amdgcn_mfma_f32_32x32x16_bf16(va, pf, o0, 0, 0, 0);
                o1 = __builtin_amdgcn_mfma_f32_32x32x16_bf16(vb, pf, o1, 0, 0, 0);
            }
        }
        __builtin_amdgcn_s_setprio(0);

        __syncthreads();   // staging landed + this iter's LDS reads done
        cur ^= 1;
    }

    // epilogue: total l, store bf16 partial O^T + fp32 (m,l)
    float lt = l_r + __shfl_xor(l_r, 32);
    const int row = wave * 32 + l31;
    unsigned short* orow = op + row * 64;
#pragma unroll
    for (int blk = 0; blk < 4; ++blk) {
        uint2 t0, t1;
        t0.x = cvt_pk_bf16(o0[blk * 4 + 0], o0[blk * 4 + 1]);
        t0.y = cvt_pk_bf16(o0[blk * 4 + 2], o0[blk * 4 + 3]);
        t1.x = cvt_pk_bf16(o1[blk * 4 + 0], o1[blk * 4 + 1]);
        t1.y = cvt_pk_bf16(o1[blk * 4 + 2], o1[blk * 4 + 3]);
        *(uint2*)(orow + 8 * blk + 4 * hi) = t0;
        *(uint2*)(orow + 32 + 8 * blk + 4 * hi) = t1;
    }
    if (hi == 0) {
        mlp[row] = m_r;
        mlp[128 + row] = lt;
    }
}

// ---------------- Combine: merge 4 bf16 partials, normalize --------------------
// 256 blocks = (qt 0..31)<<3 | b. g = (qt - 4b)&31 inverts the flash mapping.
__global__ __launch_bounds__(256) void combine_kernel(
    const unsigned short* __restrict__ opart, const float* __restrict__ mlpart,
    float* __restrict__ out)
{
    const int cid = blockIdx.x;
    const int qt = cid >> 3, b = cid & 7;
    const int g = (qt - 4 * b) & 31;
    const int pidb = g * 32 + b;      // + p*8

    const float* ml[4];
    const ushort8* ov[4];
#pragma unroll
    for (int p = 0; p < 4; ++p) {
        ml[p] = mlpart + (size_t)(pidb + p * 8) * 256;
        ov[p] = (const ushort8*)(opart + (size_t)(pidb + p * 8) * 8192);
    }

#pragma unroll
    for (int i = 0; i < 4; ++i) {
        int gidx = threadIdx.x + i * 256;   // 0..1023 groups of 8 elems
        int row = gidx >> 3;
        float m0 = ml[0][row], m1 = ml[1][row], m2 = ml[2][row], m3 = ml[3][row];
        float ms = fmaxf(fmaxf(m0, m1), fmaxf(m2, m3));
        float e0 = __builtin_amdgcn_exp2f(m0 - ms);
        float e1 = __builtin_amdgcn_exp2f(m1 - ms);
        float e2 = __builtin_amdgcn_exp2f(m2 - ms);
        float e3 = __builtin_amdgcn_exp2f(m3 - ms);
        float den = e0 * ml[0][128 + row] + e1 * ml[1][128 + row] +
                    e2 * ml[2][128 + row] + e3 * ml[3][128 + row];
        float dinv = __builtin_amdgcn_rcpf(den);
        ushort8 a0 = ov[0][gidx], a1 = ov[1][gidx], a2 = ov[2][gidx], a3 = ov[3][gidx];
        float r[8];
#pragma unroll
        for (int c = 0; c < 8; ++c)
            r[c] = (e0 * bf2f(a0[c]) + e1 * bf2f(a1[c]) +
                    e2 * bf2f(a2[c]) + e3 * bf2f(a3[c])) * dinv;
        float* gp = out + ((size_t)(b * NT) + qt * 128 + row) * NH + (gidx & 7) * 8;
        f32x4 w0, w1;
        w0[0] = r[0]; w0[1] = r[1]; w0[2] = r[2]; w0[3] = r[3];
        w1[0] = r[4]; w1[1] = r[5]; w1[2] = r[6]; w1[3] = r[7];
        *(f32x4*)(gp) = w0;
        *(f32x4*)(gp + 4) = w1;
    }
}

extern "C" void kernel_launch(void* const* d_in, const int* in_sizes, int n_in,
                              void* d_out, int out_size, void* d_ws, size_t ws_size,
                              hipStream_t stream) {
    const float* x  = (const float*)d_in[0];
    const float* Wk = (const float*)d_in[1];
    const float* Wq = (const float*)d_in[2];
    const float* Wv = (const float*)d_in[3];
    float* out = (float*)d_out;

    unsigned short* ws   = (unsigned short*)d_ws;
    const size_t qkv_elems = (size_t)NB * NT * NH;   // 2M elements each
    unsigned short* qws  = ws;
    unsigned short* kws  = qws + qkv_elems;
    unsigned short* vtws = kws + qkv_elems;
    unsigned short* Wt   = vtws + qkv_elems;              // 192*1024 bf16
    unsigned short* opart = Wt + (size_t)192 * NC;        // 1024 partials x 8192 bf16
    float* mlpart = (float*)(opart + (size_t)1024 * 8192); // 1024 x 256 f32

    wprep_kernel<<<dim3(192), dim3(256), 0, stream>>>(Wk, Wq, Wv, Wt);
    proj_kernel<<<dim3(512), dim3(256), 0, stream>>>(x, Wt, qws, kws, vtws);
    flash_kernel<<<dim3(1024), dim3(256), 0, stream>>>(qws, kws, vtws, opart, mlpart);
    combine_kernel<<<dim3(256), dim3(256), 0, stream>>>(opart, mlpart, out);
}

// Round 20
// 72.876 us; speedup vs baseline: 1.0624x; 1.0624x over previous
//
#include <hip/hip_runtime.h>
#include <hip/hip_bf16.h>

// B=8, T=4096, C=1024, HS=64. Single attention head, causal, scale = C^-0.5.
// Pipeline: wprep ; proj (counted-vmcnt) ; flash (32x32 MFMA, 32 q-rows/wave,
//           128-row q-tiles, 4-way KV split, LDS dbuf staging, in-register P
//           via cvt_pk + v_permlane32_swap, bf16 partials) ; combine.
// Q is pre-scaled by log2(e)/32 in proj, so QK^T is directly log2-domain.

typedef __attribute__((ext_vector_type(8))) short short8;
typedef __attribute__((ext_vector_type(8))) unsigned short ushort8;
typedef __attribute__((ext_vector_type(4))) float f32x4;
typedef __attribute__((ext_vector_type(16))) float f32x16;
typedef __attribute__((ext_vector_type(4))) unsigned int u32x4;

#define NB 8
#define NT 4096
#define NC 1024
#define NH 64

__device__ __forceinline__ unsigned short f2bf(float f) {
    unsigned int u = __builtin_bit_cast(unsigned int, f);
    u += 0x7fffu + ((u >> 16) & 1u);   // RNE
    return (unsigned short)(u >> 16);
}

__device__ __forceinline__ float bf2f(unsigned short u) {
    return __builtin_bit_cast(float, (unsigned int)u << 16);
}

__device__ __forceinline__ unsigned cvt_pk_bf16(float lo, float hi) {
    unsigned r;
    asm("v_cvt_pk_bf16_f32 %0, %1, %2" : "=v"(r) : "v"(lo), "v"(hi));
    return r;
}

// async global->LDS, 16B per lane; LDS dest = wave-uniform base + lane*16
#define GLOAD16(gp, lp)                                                        \
    __builtin_amdgcn_global_load_lds(                                          \
        (const __attribute__((address_space(1))) void*)(gp),                   \
        (__attribute__((address_space(3))) void*)(lp), 16, 0, 0)

// ---------------- W prep: Wt[n][c] = W_{n/64}[c][n%64] as bf16 -----------------
__global__ __launch_bounds__(256) void wprep_kernel(
    const float* __restrict__ Wk, const float* __restrict__ Wq,
    const float* __restrict__ Wv, unsigned short* __restrict__ Wt)
{
    int n = blockIdx.x;            // 0..191
    int which = n >> 6, h = n & 63;
    const float* W = (which == 0) ? Wk : (which == 1) ? Wq : Wv;
    for (int c = threadIdx.x; c < NC; c += 256)
        Wt[(size_t)n * NC + c] = f2bf(W[(size_t)c * NH + h]);
}

// ---------------- Projection GEMM: [32768 x 1024] @ [1024 x 192] ---------------
// Counted-vmcnt pipeline: BK=32, 4 LDS buffers (20 KB each), depth-2 prefetch.
__global__ __launch_bounds__(256, 2) void proj_kernel(
    const float* __restrict__ x, const unsigned short* __restrict__ Wt,
    unsigned short* __restrict__ qws, unsigned short* __restrict__ kws,
    unsigned short* __restrict__ vtws)
{
    __shared__ char lds[4][20480];   // [buf]: A at 0 (8 KB), B at 8192 (12 KB)

    const int lane = threadIdx.x & 63;
    const int wave = threadIdx.x >> 6;
    const int l15 = lane & 15;
    const int kg = lane >> 4;                  // 0..3
    const int m0 = blockIdx.x * 64;

    const int agS = (lane & 7) ^ (lane >> 3);
    const float* aSrc[2];
#pragma unroll
    for (int j = 0; j < 2; ++j) {
        int i = wave * 2 + j;
        int r = 8 * i + (lane >> 3);
        aSrc[j] = x + (size_t)(m0 + r) * NC + agS * 4;
    }
    const int bgS = (lane & 3) ^ ((lane >> 2) & 3);
    const unsigned short* bSrc[3];
#pragma unroll
    for (int j = 0; j < 3; ++j) {
        int u = wave * 3 + j;
        int r = 16 * u + (lane >> 2);
        bSrc[j] = Wt + (size_t)r * NC + bgS * 8;
    }

    f32x4 acc[12];
#pragma unroll
    for (int i = 0; i < 12; ++i) acc[i] = f32x4{0.f, 0.f, 0.f, 0.f};

#define STAGE_CHUNK(c)                                                         \
    do {                                                                       \
        char* base_ = lds[(c) & 3];                                            \
        _Pragma("unroll")                                                      \
        for (int j = 0; j < 2; ++j)                                            \
            GLOAD16(aSrc[j] + (c) * 32, base_ + (wave * 2 + j) * 1024);        \
        _Pragma("unroll")                                                      \
        for (int j = 0; j < 3; ++j)                                            \
            GLOAD16(bSrc[j] + (c) * 32, base_ + 8192 + (wave * 3 + j) * 1024); \
    } while (0)

    STAGE_CHUNK(0);
    STAGE_CHUNK(1);

    for (int kc = 0; kc < 32; ++kc) {
        if (kc < 30) {
            STAGE_CHUNK(kc + 2);
            asm volatile("s_waitcnt vmcnt(10)" ::: "memory");
        } else if (kc == 30) {
            asm volatile("s_waitcnt vmcnt(5)" ::: "memory");
        } else {
            asm volatile("s_waitcnt vmcnt(0)" ::: "memory");
        }
        __builtin_amdgcn_sched_barrier(0);
        __builtin_amdgcn_s_barrier();

        const char* Ab = lds[kc & 3];
        const char* Bb = lds[kc & 3] + 8192;
        {
            const int r = wave * 16 + l15;
            const int g0 = kg * 2;
            f32x4 a0 = *(const f32x4*)(Ab + r * 128 + ((g0 ^ (r & 7)) * 16));
            f32x4 a1 = *(const f32x4*)(Ab + r * 128 + (((g0 + 1) ^ (r & 7)) * 16));
            short8 a;
            a[0] = (short)f2bf(a0[0]); a[1] = (short)f2bf(a0[1]);
            a[2] = (short)f2bf(a0[2]); a[3] = (short)f2bf(a0[3]);
            a[4] = (short)f2bf(a1[0]); a[5] = (short)f2bf(a1[1]);
            a[6] = (short)f2bf(a1[2]); a[7] = (short)f2bf(a1[3]);
#pragma unroll
            for (int nt = 0; nt < 12; ++nt) {
                int rb = nt * 16 + l15;
                short8 bfrag = *(const short8*)(
                    Bb + rb * 64 + ((kg ^ (rb & 3)) * 16));
                acc[nt] = __builtin_amdgcn_mfma_f32_16x16x32_bf16(a, bfrag, acc[nt], 0, 0, 0);
            }
        }
    }
#undef STAGE_CHUNK

    const float cs = 0.04508422f;   // log2(e) / 32  (folded into q)
    const int crow0 = m0 + wave * 16 + (kg << 2);
#pragma unroll
    for (int nt = 0; nt < 12; ++nt) {
        int n = nt * 16 + l15;
        int which = n >> 6;
        int h = n & 63;
#pragma unroll
        for (int r = 0; r < 4; ++r) {
            int gm = crow0 + r;
            float av = acc[nt][r];
            if (which == 1) av *= cs;
            unsigned short v = f2bf(av);
            if (which == 0) {
                kws[(size_t)gm * NH + h] = v;
            } else if (which == 1) {
                qws[(size_t)gm * NH + h] = v;
            } else {
                int bb = gm >> 12, tt = gm & 4095;
                vtws[((size_t)(bb * NH + h)) * NT + tt] = v;
            }
        }
    }
}

// ---------------- Flash attention (32x32 MFMA, 128-row q-tiles, 4-way split) ----
// 1024 blocks: id = g*32 + p*8 + b  (g 0..31 -> qt via balance permutation,
// p = KV partition 0..3, b = batch = id&7 -> XCD/L2 affinity).
// Wave handles 32 q-rows. S^T = mfma32(K,Q): lane q = l&31, 16 keys/lane;
// softmax lane-local; P^T built in-register: 8 cvt_pk + 4 v_permlane32_swap
// per key-tile. O^T += mfma32(V^T, P^T). K/V dbuf via global_load_lds (32 KB).
// Partials stored as BF16 (defer-max bounds P<=2^8; ~0.4% rel err, OK).
__global__ __launch_bounds__(256, 4) void flash_kernel(
    const unsigned short* __restrict__ qws, const unsigned short* __restrict__ kws,
    const unsigned short* __restrict__ vtws,
    unsigned short* __restrict__ opart, float* __restrict__ mlpart)
{
    __shared__ unsigned short Kbuf[2][64 * 64];    // 64 keys x 64 d, 128 B rows
    __shared__ unsigned short Vbuf[2][64 * 64];    // 64 d x 64 keys (V^T)

    const int id = blockIdx.x;
    const int g = id >> 5;
    const int p = (id >> 3) & 3;
    const int b = id & 7;
    const int a = g & 7, m = g >> 3;
    const int qt = (m == 0) ? 31 - a : (m == 1) ? 16 + a : (m == 2) ? 15 - a : a;
    const int n = 2 * qt + 2;          // KV tiles for this 128-row q-tile
    const int len = (n + 3) >> 2;
    const int k0 = p * len;
    const int k1 = (k0 + len < n) ? (k0 + len) : n;

    float* mlp = mlpart + (size_t)id * 256;
    unsigned short* op = opart + (size_t)id * 8192;

    const int lane = threadIdx.x & 63;
    const int wave = threadIdx.x >> 6;
    const int l31 = lane & 31;
    const int hi = lane >> 5;
    const int rsw = lane & 7;          // row swizzle bits for frag reads

    // staging sources (pre-inverse-swizzled)
    const int sg = (lane & 7) ^ (lane >> 3);
    const unsigned short* kSrc[2];
    const unsigned short* vSrc[2];
#pragma unroll
    for (int j = 0; j < 2; ++j) {
        int r = 16 * wave + 8 * j + (lane >> 3);   // tile-local row 0..63
        kSrc[j] = kws + ((size_t)(b * NT) + r) * NH + sg * 8;
        vSrc[j] = vtws + ((size_t)(b * NH + r)) * NT + sg * 8;
    }

    // Q fragments (B-operand): lane holds Q[d = s*16 + 8*hi + j][q = l31]
    const int qmin = qt * 128 + wave * 32;
    short8 qf[4];
    {
        const char* qp = (const char*)(qws + ((size_t)(b * NT) + qmin + l31) * NH);
#pragma unroll
        for (int s = 0; s < 4; ++s)
            qf[s] = *(const short8*)(qp + s * 32 + hi * 16);
    }

    f32x16 o0, o1;                     // O^T: d-tiles 0..31 / 32..63, q = l31
#pragma unroll
    for (int i = 0; i < 16; ++i) { o0[i] = 0.f; o1[i] = 0.f; }
    float m_r = -INFINITY;
    float l_r = 0.f;                   // per-lane partial (own 32 keys per tile)

    const int kst = (k0 < n) ? k0 : (n - 1);
#pragma unroll
    for (int j = 0; j < 2; ++j) {
        int i = 2 * wave + j;
        GLOAD16(kSrc[j] + (size_t)kst * 64 * NH, (char*)Kbuf[0] + i * 1024);
        GLOAD16(vSrc[j] + (size_t)kst * 64,      (char*)Vbuf[0] + i * 1024);
    }
    __syncthreads();

    int cur = 0;
    for (int kv = k0; kv < k1; ++kv) {
        if (kv + 1 < k1) {
#pragma unroll
            for (int j = 0; j < 2; ++j) {
                int i = 2 * wave + j;
                GLOAD16(kSrc[j] + (size_t)(kv + 1) * 64 * NH,
                        (char*)Kbuf[cur ^ 1] + i * 1024);
                GLOAD16(vSrc[j] + (size_t)(kv + 1) * 64,
                        (char*)Vbuf[cur ^ 1] + i * 1024);
            }
        }

        const char* Kb = (const char*)Kbuf[cur];
        const char* Vb = (const char*)Vbuf[cur];

        // S^T = mfma32(K, Q): st0 = keys kv*64+0..31, st1 = +32..63; q = l31
        f32x16 st0, st1;
#pragma unroll
        for (int i = 0; i < 16; ++i) { st0[i] = 0.f; st1[i] = 0.f; }
        __builtin_amdgcn_s_setprio(1);
#pragma unroll
        for (int s = 0; s < 4; ++s) {
            int gl = s * 2 + hi;                    // 16B granule in 128B row
            short8 ka = *(const short8*)(Kb + l31 * 128 + ((gl ^ rsw) << 4));
            short8 kb = *(const short8*)(Kb + (32 + l31) * 128 + ((gl ^ rsw) << 4));
            st0 = __builtin_amdgcn_mfma_f32_32x32x16_bf16(ka, qf[s], st0, 0, 0, 0);
            st1 = __builtin_amdgcn_mfma_f32_32x32x16_bf16(kb, qf[s], st1, 0, 0, 0);
        }
        __builtin_amdgcn_s_setprio(0);

        // causal mask (elementwise only when tile can cross the diagonal)
        const int kb0 = kv * 64;
        if (kb0 + 63 > qmin) {
            const int qg = qmin + l31;
#pragma unroll
            for (int r = 0; r < 16; ++r) {
                int key = kb0 + (r & 3) + 8 * (r >> 2) + 4 * hi;
                if (key > qg) st0[r] = -1e30f;
                if (key + 32 > qg) st1[r] = -1e30f;
            }
        }

        // lane-local max over own 32 values (max3-friendly triples)
        float lmax;
        {
            float a0 = fmaxf(fmaxf(st0[0], st0[1]), st0[2]);
            float a1 = fmaxf(fmaxf(st0[3], st0[4]), st0[5]);
            float a2 = fmaxf(fmaxf(st0[6], st0[7]), st0[8]);
            float a3 = fmaxf(fmaxf(st0[9], st0[10]), st0[11]);
            float a4 = fmaxf(fmaxf(st0[12], st0[13]), st0[14]);
            float a5 = fmaxf(fmaxf(st0[15], st1[0]), st1[1]);
            float a6 = fmaxf(fmaxf(st1[2], st1[3]), st1[4]);
            float a7 = fmaxf(fmaxf(st1[5], st1[6]), st1[7]);
            float a8 = fmaxf(fmaxf(st1[8], st1[9]), st1[10]);
            float a9 = fmaxf(fmaxf(st1[11], st1[12]), st1[13]);
            float aa = fmaxf(st1[14], st1[15]);
            float b0 = fmaxf(fmaxf(a0, a1), a2);
            float b1 = fmaxf(fmaxf(a3, a4), a5);
            float b2 = fmaxf(fmaxf(a6, a7), a8);
            float b3 = fmaxf(a9, aa);
            lmax = fmaxf(fmaxf(b0, b1), fmaxf(b2, b3));
        }

        // defer-max: rescale only when some row grew past m+8 (rare)
        if (!__all(lmax <= m_r + 8.0f)) {
            float pmax = fmaxf(lmax, __shfl_xor(lmax, 32));
            float mn = fmaxf(m_r, pmax);
            float alpha = __builtin_amdgcn_exp2f(m_r - mn);
            m_r = mn;
            l_r *= alpha;
#pragma unroll
            for (int r = 0; r < 16; ++r) { o0[r] *= alpha; o1[r] *= alpha; }
        }

        // P = exp2(S - m); accumulate per-lane partial l (balanced tree)
#pragma unroll
        for (int r = 0; r < 16; ++r) {
            st0[r] = __builtin_amdgcn_exp2f(st0[r] - m_r);
            st1[r] = __builtin_amdgcn_exp2f(st1[r] - m_r);
        }
        {
            float q0 = (st0[0] + st0[1]) + (st0[2] + st0[3]);
            float q1 = (st0[4] + st0[5]) + (st0[6] + st0[7]);
            float q2 = (st0[8] + st0[9]) + (st0[10] + st0[11]);
            float q3 = (st0[12] + st0[13]) + (st0[14] + st0[15]);
            float q4 = (st1[0] + st1[1]) + (st1[2] + st1[3]);
            float q5 = (st1[4] + st1[5]) + (st1[6] + st1[7]);
            float q6 = (st1[8] + st1[9]) + (st1[10] + st1[11]);
            float q7 = (st1[12] + st1[13]) + (st1[14] + st1[15]);
            l_r += ((q0 + q1) + (q2 + q3)) + ((q4 + q5) + (q6 + q7));
        }

        // per key-tile: P^T B-frags via cvt_pk + permlane32_swap, then PV
        __builtin_amdgcn_s_setprio(1);
#pragma unroll
        for (int kt = 0; kt < 2; ++kt) {
            const f32x16& st = kt ? st1 : st0;
            unsigned w0 = cvt_pk_bf16(st[0], st[1]),   w1 = cvt_pk_bf16(st[2], st[3]);
            unsigned w2 = cvt_pk_bf16(st[4], st[5]),   w3 = cvt_pk_bf16(st[6], st[7]);
            unsigned w4 = cvt_pk_bf16(st[8], st[9]),   w5 = cvt_pk_bf16(st[10], st[11]);
            unsigned w6 = cvt_pk_bf16(st[12], st[13]), w7 = cvt_pk_bf16(st[14], st[15]);
            asm("v_permlane32_swap_b32 %0, %1" : "+v"(w0), "+v"(w2));
            asm("v_permlane32_swap_b32 %0, %1" : "+v"(w1), "+v"(w3));
            asm("v_permlane32_swap_b32 %0, %1" : "+v"(w4), "+v"(w6));
            asm("v_permlane32_swap_b32 %0, %1" : "+v"(w5), "+v"(w7));
            u32x4 wA, wB;
            wA[0] = w0; wA[1] = w1; wA[2] = w2; wA[3] = w3;
            wB[0] = w4; wB[1] = w5; wB[2] = w6; wB[3] = w7;
            short8 pfA = __builtin_bit_cast(short8, wA);
            short8 pfB = __builtin_bit_cast(short8, wB);
#pragma unroll
            for (int w = 0; w < 2; ++w) {           // key window within tile
                short8 pf = w ? pfB : pfA;
                int gv = (kt * 2 + w) * 2 + hi;     // granule over 64-key row
                short8 va = *(const short8*)(Vb + l31 * 128 + ((gv ^ rsw) << 4));
                short8 vb = *(const short8*)(Vb + (32 + l31) * 128 + ((gv ^ rsw) << 4));
                o0 = __builtin_amdgcn_mfma_f32_32x32x16_bf16(va, pf, o0, 0, 0, 0);
                o1 = __builtin_amdgcn_mfma_f32_32x32x16_bf16(vb, pf, o1, 0, 0, 0);
            }
        }
        __builtin_amdgcn_s_setprio(0);

        // barrier needed only if another tile follows (staging/read handoff);
        // the final iteration's epilogue touches global memory only.
        if (kv + 1 < k1) __syncthreads();
        cur ^= 1;
    }

    // epilogue: total l, store bf16 partial O^T + fp32 (m,l)
    float lt = l_r + __shfl_xor(l_r, 32);
    const int row = wave * 32 + l31;
    unsigned short* orow = op + row * 64;
#pragma unroll
    for (int blk = 0; blk < 4; ++blk) {
        uint2 t0, t1;
        t0.x = cvt_pk_bf16(o0[blk * 4 + 0], o0[blk * 4 + 1]);
        t0.y = cvt_pk_bf16(o0[blk * 4 + 2], o0[blk * 4 + 3]);
        t1.x = cvt_pk_bf16(o1[blk * 4 + 0], o1[blk * 4 + 1]);
        t1.y = cvt_pk_bf16(o1[blk * 4 + 2], o1[blk * 4 + 3]);
        *(uint2*)(orow + 8 * blk + 4 * hi) = t0;
        *(uint2*)(orow + 32 + 8 * blk + 4 * hi) = t1;
    }
    if (hi == 0) {
        mlp[row] = m_r;
        mlp[128 + row] = lt;
    }
}

// ---------------- Combine: merge 4 bf16 partials, normalize --------------------
// 256 blocks = (qt 0..31)<<3 | b. O = sum_p e_p*O_p / sum_p e_p*l_p.
__global__ __launch_bounds__(256) void combine_kernel(
    const unsigned short* __restrict__ opart, const float* __restrict__ mlpart,
    float* __restrict__ out)
{
    const int cid = blockIdx.x;
    const int qt = cid >> 3, b = cid & 7;
    int g;
    if (qt >= 24) g = 31 - qt;
    else if (qt >= 16) g = 8 + (qt - 16);
    else if (qt >= 8) g = 16 + (15 - qt);
    else g = 24 + qt;
    const int pidb = g * 32 + b;      // + p*8

    const float* ml[4];
    const ushort8* ov[4];
#pragma unroll
    for (int p = 0; p < 4; ++p) {
        ml[p] = mlpart + (size_t)(pidb + p * 8) * 256;
        ov[p] = (const ushort8*)(opart + (size_t)(pidb + p * 8) * 8192);
    }

#pragma unroll
    for (int i = 0; i < 4; ++i) {
        int gidx = threadIdx.x + i * 256;   // 0..1023 groups of 8 elems
        int row = gidx >> 3;
        float m0 = ml[0][row], m1 = ml[1][row], m2 = ml[2][row], m3 = ml[3][row];
        float ms = fmaxf(fmaxf(m0, m1), fmaxf(m2, m3));
        float e0 = __builtin_amdgcn_exp2f(m0 - ms);
        float e1 = __builtin_amdgcn_exp2f(m1 - ms);
        float e2 = __builtin_amdgcn_exp2f(m2 - ms);
        float e3 = __builtin_amdgcn_exp2f(m3 - ms);
        float den = e0 * ml[0][128 + row] + e1 * ml[1][128 + row] +
                    e2 * ml[2][128 + row] + e3 * ml[3][128 + row];
        float dinv = __builtin_amdgcn_rcpf(den);
        ushort8 a0 = ov[0][gidx], a1 = ov[1][gidx], a2 = ov[2][gidx], a3 = ov[3][gidx];
        float r[8];
#pragma unroll
        for (int c = 0; c < 8; ++c)
            r[c] = (e0 * bf2f(a0[c]) + e1 * bf2f(a1[c]) +
                    e2 * bf2f(a2[c]) + e3 * bf2f(a3[c])) * dinv;
        float* gp = out + ((size_t)(b * NT) + qt * 128 + row) * NH + (gidx & 7) * 8;
        f32x4 w0, w1;
        w0[0] = r[0]; w0[1] = r[1]; w0[2] = r[2]; w0[3] = r[3];
        w1[0] = r[4]; w1[1] = r[5]; w1[2] = r[6]; w1[3] = r[7];
        *(f32x4*)(gp) = w0;
        *(f32x4*)(gp + 4) = w1;
    }
}

extern "C" void kernel_launch(void* const* d_in, const int* in_sizes, int n_in,
                              void* d_out, int out_size, void* d_ws, size_t ws_size,
                              hipStream_t stream) {
    const float* x  = (const float*)d_in[0];
    const float* Wk = (const float*)d_in[1];
    const float* Wq = (const float*)d_in[2];
    const float* Wv = (const float*)d_in[3];
    float* out = (float*)d_out;

    unsigned short* ws   = (unsigned short*)d_ws;
    const size_t qkv_elems = (size_t)NB * NT * NH;   // 2M elements each
    unsigned short* qws  = ws;
    unsigned short* kws  = qws + qkv_elems;
    unsigned short* vtws = kws + qkv_elems;
    unsigned short* Wt   = vtws + qkv_elems;              // 192*1024 bf16
    unsigned short* opart = Wt + (size_t)192 * NC;        // 1024 partials x 8192 bf16
    float* mlpart = (float*)(opart + (size_t)1024 * 8192); // 1024 x 256 f32

    wprep_kernel<<<dim3(192), dim3(256), 0, stream>>>(Wk, Wq, Wv, Wt);
    proj_kernel<<<dim3(512), dim3(256), 0, stream>>>(x, Wt, qws, kws, vtws);
    flash_kernel<<<dim3(1024), dim3(256), 0, stream>>>(qws, kws, vtws, opart, mlpart);
    combine_kernel<<<dim3(256), dim3(256), 0, stream>>>(opart, mlpart, out);
}